// Round 23
// baseline (209.208 us; speedup 1.0000x reference)
//
#include <hip/hip_runtime.h>

#define HID 40
#define RBKT 196          // buckets of 512 nodes: covers n <= 100352
#define BSH 9             // bucket shift (512 nodes per bucket)
#define CAP 12288         // per-bucket edge capacity (mean 8192, +45 sigma)
#define EPB 4096          // edges per block in binning pass

// ---------------- types / helpers ----------------

typedef __attribute__((ext_vector_type(4))) unsigned uv4;
typedef __attribute__((ext_vector_type(8))) __bf16 bf16x8;
typedef __attribute__((ext_vector_type(8))) unsigned short usv8;
typedef __attribute__((ext_vector_type(4))) float f32x4;

__device__ inline unsigned pack2_bf16(float a, float b) {
    unsigned ua = __float_as_uint(a);
    unsigned ub = __float_as_uint(b);
    ua = (ua + 0x7fffu + ((ua >> 16) & 1u)) >> 16;            // RNE, low half
    ub = (ub + 0x7fffu + ((ub >> 16) & 1u)) & 0xffff0000u;    // RNE, high half
    return ua | ub;
}

__device__ inline void acc8_bf16(float* acc, uint4 v) {
    acc[0] += __uint_as_float(v.x << 16);
    acc[1] += __uint_as_float(v.x & 0xffff0000u);
    acc[2] += __uint_as_float(v.y << 16);
    acc[3] += __uint_as_float(v.y & 0xffff0000u);
    acc[4] += __uint_as_float(v.z << 16);
    acc[5] += __uint_as_float(v.z & 0xffff0000u);
    acc[6] += __uint_as_float(v.w << 16);
    acc[7] += __uint_as_float(v.w & 0xffff0000u);
}

// W -> MFMA B-fragments for one layer (device helper, lane l of 64)
__device__ inline void wprep_dev(const float* __restrict__ W,
                                 unsigned* __restrict__ wtab, int INF, int l) {
    int lr = l & 15, lg = l >> 4;
    int kstn = (INF > 32) ? 2 : 1;
    for (int kst = 0; kst < kstn; kst++) {
        for (int ct = 0; ct < 3; ct++) {
            unsigned short v[8];
            #pragma unroll
            for (int i = 0; i < 8; i++) {
                int kb = kst * 32 + lg * 8 + i;
                int col = ct * 16 + lr;
                float f = (kb < INF && col < 40) ? W[kb * 40 + col] : 0.f;
                v[i] = (unsigned short)(pack2_bf16(f, 0.f) & 0xffffu);
            }
            uint4 u;
            u.x = (unsigned)v[0] | ((unsigned)v[1] << 16);
            u.y = (unsigned)v[2] | ((unsigned)v[3] << 16);
            u.z = (unsigned)v[4] | ((unsigned)v[5] << 16);
            u.w = (unsigned)v[6] | ((unsigned)v[7] << 16);
            reinterpret_cast<uint4*>(wtab)[(kst * 3 + ct) * 64 + l] = u;
        }
    }
}

// one block, 256 threads: clears + all three W-fragment tables
__global__ void prep_kernel(int* __restrict__ bucket_cnt, float* __restrict__ g_sum, int G,
                            const float* __restrict__ W1, const float* __restrict__ W2,
                            const float* __restrict__ W3,
                            unsigned* __restrict__ wtab1, unsigned* __restrict__ wtab2,
                            unsigned* __restrict__ wtab3) {
    int t = threadIdx.x;
    if (t < RBKT) bucket_cnt[t] = 0;
    if (t < G) g_sum[t] = 0.f;
    int w = t >> 6, l = t & 63;
    if (w == 1) wprep_dev(W1, wtab1, 30, l);
    else if (w == 2) wprep_dev(W2, wtab2, 40, l);
    else if (w == 3) wprep_dev(W3, wtab3, 40, l);
}

// ---------------- CSR build (two-level bucketed, rows split by src half) ----------------

__global__ __launch_bounds__(256) void binA_kernel(
        const int* __restrict__ esrc, const int* __restrict__ edst, int E,
        int* __restrict__ bucket_cnt, int* __restrict__ bucket_data) {
    __shared__ int cnt_l[RBKT];
    __shared__ int base_l[RBKT];
    int t = threadIdx.x;
    for (int b = t; b < RBKT; b += 256) cnt_l[b] = 0;
    __syncthreads();
    int e0 = blockIdx.x * EPB;
    int e1 = min(e0 + EPB, E);
    for (int e = e0 + t; e < e1; e += 256) {
        atomicAdd(&cnt_l[edst[e] >> BSH], 1);
    }
    __syncthreads();
    for (int b = t; b < RBKT; b += 256) {
        int c = cnt_l[b];
        base_l[b] = (c > 0) ? atomicAdd(&bucket_cnt[b], c) : 0;
        cnt_l[b] = 0;
    }
    __syncthreads();
    for (int e = e0 + t; e < e1; e += 256) {
        int d = edst[e];
        int s = esrc[e];
        int b = d >> BSH;
        int off = base_l[b] + atomicAdd(&cnt_l[b], 1);
        if (off < CAP) bucket_data[(size_t)b * CAP + off] = (s << BSH) | (d & 511);
    }
}

__global__ void scan_buckets_kernel(const int* __restrict__ cnt, int* __restrict__ base) {
    __shared__ int s[256];
    int t = threadIdx.x;
    int c = (t < RBKT) ? min(cnt[t], CAP) : 0;
    s[t] = c;
    __syncthreads();
    for (int off = 1; off < 256; off <<= 1) {
        int y = (t >= off) ? s[t - off] : 0;
        __syncthreads();
        s[t] += y;
        __syncthreads();
    }
    if (t < RBKT) base[t] = s[t] - c;
    if (t == RBKT - 1) base[RBKT] = s[t];
}

// builds rowptr/csr/dinv + mid (lo/hi src split) + bucket-local permutation
// nperm sorted by key = (graph offset within bucket, clamped 0..7)*64 + deg.
__global__ __launch_bounds__(256) void buildB_kernel(
        const int* __restrict__ bucket_cnt, const int* __restrict__ bucket_base,
        const int* __restrict__ bucket_data, const int* __restrict__ batch,
        int* __restrict__ rowptr, int* __restrict__ mid, int* __restrict__ csr,
        float* __restrict__ dinv, int* __restrict__ nperm, int n, int half) {
    __shared__ int deg_l[512];
    __shared__ int deg_lo[512];
    __shared__ int off_lo[512];
    __shared__ int off_hi[512];
    __shared__ int ps[256];
    int r = blockIdx.x;
    int t = threadIdx.x;
    int cnt = min(bucket_cnt[r], CAP);
    int base = bucket_base[r];
    int node0 = r << BSH;
    int nr = min(512, n - node0);
    if (nr <= 0) return;
    for (int i = t; i < 512; i += 256) { deg_l[i] = 0; deg_lo[i] = 0; }
    __syncthreads();
    const int* data = bucket_data + (size_t)r * CAP;
    for (int e = t; e < cnt; e += 256) {
        int v = data[e];
        atomicAdd(&deg_l[v & 511], 1);
        if ((v >> BSH) < half) atomicAdd(&deg_lo[v & 511], 1);
    }
    __syncthreads();
    int a0 = deg_l[2 * t], a1 = deg_l[2 * t + 1];
    ps[t] = a0 + a1;
    __syncthreads();
    for (int off = 1; off < 256; off <<= 1) {
        int y = (t >= off) ? ps[t - off] : 0;
        __syncthreads();
        ps[t] += y;
        __syncthreads();
    }
    int excl = ps[t] - (a0 + a1);
    off_lo[2 * t] = excl;
    off_lo[2 * t + 1] = excl + a0;
    off_hi[2 * t] = excl + deg_lo[2 * t];
    off_hi[2 * t + 1] = excl + a0 + deg_lo[2 * t + 1];
    __syncthreads();
    for (int i = t; i < nr; i += 256) {
        int rp = base + off_lo[i];
        rowptr[node0 + i] = rp;
        mid[node0 + i] = rp + deg_lo[i];
        dinv[node0 + i] = rsqrtf((float)(deg_l[i] + 1));
    }
    if (r == RBKT - 1 && t == 0) rowptr[n] = base + cnt;
    __syncthreads();
    for (int e = t; e < cnt; e += 256) {
        int v = data[e];
        int s = v >> BSH;
        int d = v & 511;
        int p = (s < half) ? atomicAdd(&off_lo[d], 1) : atomicAdd(&off_hi[d], 1);
        csr[base + p] = s;
    }
    // ---- bucket-local (graph,degree)-sorted permutation ----
    __syncthreads();
    for (int i = t; i < 512; i += 256) off_lo[i] = 0;       // khist
    __syncthreads();
    int gbase = batch[node0];
    for (int i = t; i < nr; i += 256) {
        int key = min(batch[node0 + i] - gbase, 7) * 64 + min(deg_l[i], 63);
        deg_lo[i] = key;                                     // stash key
        atomicAdd(&off_lo[key], 1);
    }
    __syncthreads();
    int c0 = off_lo[2 * t], c1 = off_lo[2 * t + 1];
    ps[t] = c0 + c1;
    __syncthreads();
    for (int off = 1; off < 256; off <<= 1) {
        int y = (t >= off) ? ps[t - off] : 0;
        __syncthreads();
        ps[t] += y;
        __syncthreads();
    }
    int ex2 = ps[t] - (c0 + c1);
    off_hi[2 * t] = ex2;
    off_hi[2 * t + 1] = ex2 + c0;
    __syncthreads();
    for (int i = t; i < nr; i += 256) {
        int p = atomicAdd(&off_hi[deg_lo[i]], 1);
        nperm[node0 + p] = node0 + i;
    }
}

// ---------------- layer kernels ----------------

// x (f32, n x 30) * dinv -> bf16 table, 16 uints/row (32 slots, last 2 zero)
__global__ __launch_bounds__(256) void scale_bf16_kernel(
        const float* __restrict__ x, const float* __restrict__ dinv,
        unsigned* __restrict__ xs, int n) {
    int t = blockIdx.x * blockDim.x + threadIdx.x;
    int i = t >> 4, p = t & 15;
    if (i >= n) return;
    float a = 0.f, b = 0.f;
    if (p < 15) {
        float d = dinv[i];
        a = x[i * 30 + 2 * p] * d;
        b = x[i * 30 + 2 * p + 1] * d;
    }
    xs[(size_t)i * 16 + p] = pack2_bf16(a, b);
}

// Fused layer (round-20/22 structure + bucket-local degree-balanced nperm):
// 64 perm'd nodes/block, 64*RQ threads; gather (slice-per-thread, half-split,
// unroll 4) -> packed-bf16 LDS tile -> MFMA transform (precomputed wtab) ->
// bias+relu+dinv epilogue -> direct table stores (or pool+linear).
template <int INF, int RQ, bool POOL>
__global__ __launch_bounds__(64 * RQ) void fused_layer_kernel(
        const unsigned* __restrict__ xs, const unsigned* __restrict__ wtab,
        const int* __restrict__ rowptr, const int* __restrict__ mid,
        const int* __restrict__ csr, const float* __restrict__ dinv,
        const int* __restrict__ nperm,
        const float* __restrict__ bias, const float* __restrict__ lin_w,
        const int* __restrict__ batch,
        unsigned* __restrict__ out, float* __restrict__ g_sum, int n) {
    constexpr int KST = (INF > 32) ? 2 : 1;
    constexpr int TS  = (RQ == 4) ? 5 : 7;     // tile stride (uint4), conflict pad
    __shared__ uint4 tile[64 * TS];
    __shared__ float sarr[POOL ? 64 : 1];
    const int tid = threadIdx.x;
    const uint4* tab = reinterpret_cast<const uint4*>(xs);

    // ---- gather phase ----
    {
        const int node_l = tid / RQ, q = tid - node_l * RQ;
        const int j = blockIdx.x * 64 + node_l;
        if (j < n) {
            const int gi = nperm[j];
            float acc[8];
            {
                uint4 v = tab[(size_t)gi * RQ + q];        // self loop
                acc[0] = __uint_as_float(v.x << 16);
                acc[1] = __uint_as_float(v.x & 0xffff0000u);
                acc[2] = __uint_as_float(v.y << 16);
                acc[3] = __uint_as_float(v.y & 0xffff0000u);
                acc[4] = __uint_as_float(v.z << 16);
                acc[5] = __uint_as_float(v.z & 0xffff0000u);
                acc[6] = __uint_as_float(v.w << 16);
                acc[7] = __uint_as_float(v.w & 0xffff0000u);
            }
            int e0 = rowptr[gi], m = mid[gi], e1 = rowptr[gi + 1];
            int e = e0;
            for (; e + 4 <= m; e += 4) {                   // phase A: lo half-table
                int s0 = csr[e], s1 = csr[e + 1], s2 = csr[e + 2], s3 = csr[e + 3];
                uint4 v0 = tab[(size_t)s0 * RQ + q];
                uint4 v1 = tab[(size_t)s1 * RQ + q];
                uint4 v2 = tab[(size_t)s2 * RQ + q];
                uint4 v3 = tab[(size_t)s3 * RQ + q];
                acc8_bf16(acc, v0);
                acc8_bf16(acc, v1);
                acc8_bf16(acc, v2);
                acc8_bf16(acc, v3);
            }
            for (; e < m; e++) acc8_bf16(acc, tab[(size_t)csr[e] * RQ + q]);
            for (; e + 4 <= e1; e += 4) {                  // phase B: hi half-table
                int s0 = csr[e], s1 = csr[e + 1], s2 = csr[e + 2], s3 = csr[e + 3];
                uint4 v0 = tab[(size_t)s0 * RQ + q];
                uint4 v1 = tab[(size_t)s1 * RQ + q];
                uint4 v2 = tab[(size_t)s2 * RQ + q];
                uint4 v3 = tab[(size_t)s3 * RQ + q];
                acc8_bf16(acc, v0);
                acc8_bf16(acc, v1);
                acc8_bf16(acc, v2);
                acc8_bf16(acc, v3);
            }
            for (; e < e1; e++) acc8_bf16(acc, tab[(size_t)csr[e] * RQ + q]);
            float d = dinv[gi];
            uint4 o;
            o.x = pack2_bf16(acc[0] * d, acc[1] * d);
            o.y = pack2_bf16(acc[2] * d, acc[3] * d);
            o.z = pack2_bf16(acc[4] * d, acc[5] * d);
            o.w = pack2_bf16(acc[6] * d, acc[7] * d);
            tile[node_l * TS + q] = o;
        }
    }
    __syncthreads();

    // ---- MFMA transform phase (waves 0-3; wave 4, if any, skips) ----
    const int wv = tid >> 6, l = tid & 63, lr = l & 15, lg = l >> 4;
    if (wv < 4) {
        const uv4* wt = reinterpret_cast<const uv4*>(wtab);
        usv8 wf[KST][3];
        #pragma unroll
        for (int kst = 0; kst < KST; kst++) {
            #pragma unroll
            for (int ct = 0; ct < 3; ct++) {
                wf[kst][ct] = __builtin_bit_cast(usv8, wt[(kst * 3 + ct) * 64 + l]);
            }
        }
        const int arow_l = wv * 16 + lr;
        bf16x8 a0 = __builtin_bit_cast(bf16x8, tile[arow_l * TS + lg]);
        bf16x8 a1;
        if constexpr (KST == 2) {
            uint4 z4 = {0u, 0u, 0u, 0u};
            uint4 a1q = (lg == 0) ? tile[arow_l * TS + 4] : z4;
            a1 = __builtin_bit_cast(bf16x8, a1q);
        }
        f32x4 acc[3];
        #pragma unroll
        for (int ct = 0; ct < 3; ct++) {
            f32x4 z = {0.f, 0.f, 0.f, 0.f};
            acc[ct] = __builtin_amdgcn_mfma_f32_16x16x32_bf16(
                a0, __builtin_bit_cast(bf16x8, wf[0][ct]), z, 0, 0, 0);
            if constexpr (KST == 2) {
                acc[ct] = __builtin_amdgcn_mfma_f32_16x16x32_bf16(
                    a1, __builtin_bit_cast(bf16x8, wf[1][ct]), acc[ct], 0, 0, 0);
            }
        }
        int noder[4]; float dr[4]; bool vr[4];
        #pragma unroll
        for (int r = 0; r < 4; r++) {
            int jg = blockIdx.x * 64 + wv * 16 + lg * 4 + r;
            vr[r] = (jg < n);
            noder[r] = vr[r] ? nperm[jg] : 0;
            dr[r] = vr[r] ? dinv[noder[r]] : 0.f;
        }
        if (!POOL) {
            #pragma unroll
            for (int ct = 0; ct < 3; ct++) {
                int col = ct * 16 + lr;
                float bc = (col < 40) ? bias[col] : 0.f;
                #pragma unroll
                for (int r = 0; r < 4; r++) {
                    float v = fmaxf(acc[ct][r] + bc, 0.f) * dr[r];
                    float pv = __shfl_xor(v, 1, 64);
                    if (((lr & 1) == 0) && vr[r] && col < 40) {
                        out[(size_t)noder[r] * 20 + ct * 8 + (lr >> 1)] = pack2_bf16(v, pv);
                    }
                }
            }
        } else {
            float s[4] = {0.f, 0.f, 0.f, 0.f};
            #pragma unroll
            for (int ct = 0; ct < 3; ct++) {
                int col = ct * 16 + lr;
                float bc = (col < 40) ? bias[col] : 0.f;
                float lwv = (col < 40) ? lin_w[col] : 0.f;
                #pragma unroll
                for (int r = 0; r < 4; r++)
                    s[r] += fmaxf(acc[ct][r] + bc, 0.f) * lwv;
            }
            #pragma unroll
            for (int r = 0; r < 4; r++) if (!vr[r]) s[r] = 0.f;
            #pragma unroll
            for (int mask = 1; mask <= 8; mask <<= 1) {
                #pragma unroll
                for (int r = 0; r < 4; r++) s[r] += __shfl_xor(s[r], mask, 64);
            }
            if (lr == 0) {
                #pragma unroll
                for (int r = 0; r < 4; r++) sarr[wv * 16 + lg * 4 + r] = s[r];
            }
        }
    }
    if (POOL) {
        __syncthreads();
        if (tid < 64) {
            float ss = sarr[tid];
            int j2 = blockIdx.x * 64 + tid;
            bool v2 = (j2 < n);
            int node2 = v2 ? nperm[j2] : 0;
            int gg = batch[v2 ? node2 : (n - 1)];
            if (!v2) ss = 0.f;
            int g0 = __shfl(gg, 0, 64);
            if (__all(gg == g0)) {
                #pragma unroll
                for (int off2 = 32; off2 > 0; off2 >>= 1) ss += __shfl_xor(ss, off2, 64);
                if (tid == 0) atomicAdd(&g_sum[g0], ss);
            } else {
                if (v2) atomicAdd(&g_sum[gg], ss);
            }
        }
    }
}

__global__ void finalize_kernel(const float* __restrict__ g_sum,
                                const int* __restrict__ batch,
                                const float* __restrict__ lin_b,
                                float* __restrict__ out, int n, int G) {
    int b = blockIdx.x * blockDim.x + threadIdx.x;
    if (b >= G) return;
    int lo = 0, hi = n;
    while (lo < hi) { int m = (lo + hi) >> 1; if (batch[m] < b) lo = m + 1; else hi = m; }
    int lo2 = lo, hi2 = n;
    while (lo2 < hi2) { int m = (lo2 + hi2) >> 1; if (batch[m] < b + 1) lo2 = m + 1; else hi2 = m; }
    int cnt = lo2 - lo;
    out[b] = g_sum[b] / (float)(cnt > 0 ? cnt : 1) + lin_b[0];
}

// ---------------- launch ----------------

static inline size_t align_up(size_t v, size_t a) { return (v + a - 1) / a * a; }

extern "C" void kernel_launch(void* const* d_in, const int* in_sizes, int n_in,
                              void* d_out, int out_size, void* d_ws, size_t ws_size,
                              hipStream_t stream) {
    const float* x      = (const float*)d_in[0];
    const int*   esrc   = (const int*)d_in[1];
    const int*   batch  = (const int*)d_in[2];
    const float* W1     = (const float*)d_in[3];
    const float* b1     = (const float*)d_in[4];
    const float* W2     = (const float*)d_in[5];
    const float* b2     = (const float*)d_in[6];
    const float* W3     = (const float*)d_in[7];
    const float* b3     = (const float*)d_in[8];
    const float* lin_w  = (const float*)d_in[9];
    const float* lin_b  = (const float*)d_in[10];
    float* out = (float*)d_out;

    const int n = in_sizes[0] / 30;
    const int E = in_sizes[1] / 2;
    const int G = out_size;
    const int* edst = esrc + E;

    char* w = (char*)d_ws;
    size_t off = 0;
    auto take = [&](size_t bytes) { size_t o = off; off = align_up(off + bytes, 256); return (void*)(w + o); };
    int*      bucket_cnt  = (int*)take((size_t)RBKT * 4);
    int*      bucket_base = (int*)take((size_t)(RBKT + 1) * 4);
    int*      rowptr      = (int*)take((size_t)(n + 1) * 4);
    int*      mid         = (int*)take((size_t)n * 4);
    float*    dinv        = (float*)take((size_t)n * 4);
    int*      csr         = (int*)take((size_t)E * 4);
    float*    g_sum       = (float*)take((size_t)G * 4);
    int*      nperm       = (int*)take((size_t)n * 4);
    unsigned* wtab1       = (unsigned*)take((size_t)3 * 64 * 16);
    unsigned* wtab2       = (unsigned*)take((size_t)6 * 64 * 16);
    unsigned* wtab3       = (unsigned*)take((size_t)6 * 64 * 16);
    // bucket_data (9.6 MB) dead after buildB; alias with xs1 (6.4 MB)
    size_t bd = (size_t)RBKT * CAP * 4;
    size_t x1 = (size_t)n * 16 * 4;
    void* shared_region = take(bd > x1 ? bd : x1);
    int*      bucket_data = (int*)shared_region;
    unsigned* xs1         = (unsigned*)shared_region;
    unsigned* tbA         = (unsigned*)take((size_t)n * 20 * 4);  // layer-2 table
    unsigned* tbB         = (unsigned*)take((size_t)n * 20 * 4);  // layer-3 table
    (void)ws_size;

    // clears + W-fragment tables in one launch
    prep_kernel<<<1, 256, 0, stream>>>(bucket_cnt, g_sum, G, W1, W2, W3,
                                       wtab1, wtab2, wtab3);

    binA_kernel<<<(E + EPB - 1) / EPB, 256, 0, stream>>>(esrc, edst, E, bucket_cnt, bucket_data);
    scan_buckets_kernel<<<1, 256, 0, stream>>>(bucket_cnt, bucket_base);
    buildB_kernel<<<RBKT, 256, 0, stream>>>(bucket_cnt, bucket_base, bucket_data, batch,
                                            rowptr, mid, csr, dinv, nperm, n, n / 2);

    int nblk = (n + 63) / 64;

    // layer 1: fused gather+MFMA transform, 30->40 (256 threads)
    scale_bf16_kernel<<<((size_t)n * 16 + 255) / 256, 256, 0, stream>>>(x, dinv, xs1, n);
    fused_layer_kernel<30, 4, false><<<nblk, 256, 0, stream>>>(
        xs1, wtab1, rowptr, mid, csr, dinv, nperm, b1, nullptr, nullptr, tbA, nullptr, n);
    // layer 2: fused, 40->40 (320 threads)
    fused_layer_kernel<40, 5, false><<<nblk, 320, 0, stream>>>(
        tbA, wtab2, rowptr, mid, csr, dinv, nperm, b2, nullptr, nullptr, tbB, nullptr, n);
    // layer 3: fused + pool + linear (320 threads)
    fused_layer_kernel<40, 5, true><<<nblk, 320, 0, stream>>>(
        tbB, wtab3, rowptr, mid, csr, dinv, nperm, b3, lin_w, batch, nullptr, g_sum, n);

    finalize_kernel<<<1, 256, 0, stream>>>(g_sum, batch, lin_b, out, n, G);
}

// Round 24
// 195.990 us; speedup vs baseline: 1.0674x; 1.0674x over previous
//
#include <hip/hip_runtime.h>

#define HID 40
#define RBKT 196          // buckets of 512 nodes: covers n <= 100352
#define BSH 9             // bucket shift (512 nodes per bucket)
#define CAP 12288         // per-bucket edge capacity (mean 8192, +45 sigma)
#define EPB 4096          // edges per block in binning pass

// ---------------- types / helpers ----------------

typedef __attribute__((ext_vector_type(4))) unsigned uv4;
typedef __attribute__((ext_vector_type(8))) __bf16 bf16x8;
typedef __attribute__((ext_vector_type(8))) unsigned short usv8;
typedef __attribute__((ext_vector_type(4))) float f32x4;

__device__ inline unsigned pack2_bf16(float a, float b) {
    unsigned ua = __float_as_uint(a);
    unsigned ub = __float_as_uint(b);
    ua = (ua + 0x7fffu + ((ua >> 16) & 1u)) >> 16;            // RNE, low half
    ub = (ub + 0x7fffu + ((ub >> 16) & 1u)) & 0xffff0000u;    // RNE, high half
    return ua | ub;
}

__device__ inline void acc8_bf16(float* acc, uint4 v) {
    acc[0] += __uint_as_float(v.x << 16);
    acc[1] += __uint_as_float(v.x & 0xffff0000u);
    acc[2] += __uint_as_float(v.y << 16);
    acc[3] += __uint_as_float(v.y & 0xffff0000u);
    acc[4] += __uint_as_float(v.z << 16);
    acc[5] += __uint_as_float(v.z & 0xffff0000u);
    acc[6] += __uint_as_float(v.w << 16);
    acc[7] += __uint_as_float(v.w & 0xffff0000u);
}

// W -> MFMA B-fragments for one layer (device helper, lane l of 64)
__device__ inline void wprep_dev(const float* __restrict__ W,
                                 unsigned* __restrict__ wtab, int INF, int l) {
    int lr = l & 15, lg = l >> 4;
    int kstn = (INF > 32) ? 2 : 1;
    for (int kst = 0; kst < kstn; kst++) {
        for (int ct = 0; ct < 3; ct++) {
            unsigned short v[8];
            #pragma unroll
            for (int i = 0; i < 8; i++) {
                int kb = kst * 32 + lg * 8 + i;
                int col = ct * 16 + lr;
                float f = (kb < INF && col < 40) ? W[kb * 40 + col] : 0.f;
                v[i] = (unsigned short)(pack2_bf16(f, 0.f) & 0xffffu);
            }
            uint4 u;
            u.x = (unsigned)v[0] | ((unsigned)v[1] << 16);
            u.y = (unsigned)v[2] | ((unsigned)v[3] << 16);
            u.z = (unsigned)v[4] | ((unsigned)v[5] << 16);
            u.w = (unsigned)v[6] | ((unsigned)v[7] << 16);
            reinterpret_cast<uint4*>(wtab)[(kst * 3 + ct) * 64 + l] = u;
        }
    }
}

// one block, 256 threads: clears + all three W-fragment tables
__global__ void prep_kernel(int* __restrict__ bucket_cnt, float* __restrict__ g_sum, int G,
                            const float* __restrict__ W1, const float* __restrict__ W2,
                            const float* __restrict__ W3,
                            unsigned* __restrict__ wtab1, unsigned* __restrict__ wtab2,
                            unsigned* __restrict__ wtab3) {
    int t = threadIdx.x;
    if (t < RBKT) bucket_cnt[t] = 0;
    if (t < G) g_sum[t] = 0.f;
    int w = t >> 6, l = t & 63;
    if (w == 1) wprep_dev(W1, wtab1, 30, l);
    else if (w == 2) wprep_dev(W2, wtab2, 40, l);
    else if (w == 3) wprep_dev(W3, wtab3, 40, l);
}

// ---------------- CSR build (two-level bucketed, rows split by src half) ----------------

__global__ __launch_bounds__(256) void binA_kernel(
        const int* __restrict__ esrc, const int* __restrict__ edst, int E,
        int* __restrict__ bucket_cnt, int* __restrict__ bucket_data) {
    __shared__ int cnt_l[RBKT];
    __shared__ int base_l[RBKT];
    int t = threadIdx.x;
    for (int b = t; b < RBKT; b += 256) cnt_l[b] = 0;
    __syncthreads();
    int e0 = blockIdx.x * EPB;
    int e1 = min(e0 + EPB, E);
    for (int e = e0 + t; e < e1; e += 256) {
        atomicAdd(&cnt_l[edst[e] >> BSH], 1);
    }
    __syncthreads();
    for (int b = t; b < RBKT; b += 256) {
        int c = cnt_l[b];
        base_l[b] = (c > 0) ? atomicAdd(&bucket_cnt[b], c) : 0;
        cnt_l[b] = 0;
    }
    __syncthreads();
    for (int e = e0 + t; e < e1; e += 256) {
        int d = edst[e];
        int s = esrc[e];
        int b = d >> BSH;
        int off = base_l[b] + atomicAdd(&cnt_l[b], 1);
        if (off < CAP) bucket_data[(size_t)b * CAP + off] = (s << BSH) | (d & 511);
    }
}

__global__ void scan_buckets_kernel(const int* __restrict__ cnt, int* __restrict__ base) {
    __shared__ int s[256];
    int t = threadIdx.x;
    int c = (t < RBKT) ? min(cnt[t], CAP) : 0;
    s[t] = c;
    __syncthreads();
    for (int off = 1; off < 256; off <<= 1) {
        int y = (t >= off) ? s[t - off] : 0;
        __syncthreads();
        s[t] += y;
        __syncthreads();
    }
    if (t < RBKT) base[t] = s[t] - c;
    if (t == RBKT - 1) base[RBKT] = s[t];
}

// builds rowptr/csr/dinv + mid: each row stores srcs < half first, then >= half
__global__ __launch_bounds__(256) void buildB_kernel(
        const int* __restrict__ bucket_cnt, const int* __restrict__ bucket_base,
        const int* __restrict__ bucket_data,
        int* __restrict__ rowptr, int* __restrict__ mid, int* __restrict__ csr,
        float* __restrict__ dinv, int n, int half) {
    __shared__ int deg_l[512];
    __shared__ int deg_lo[512];
    __shared__ int off_lo[512];
    __shared__ int off_hi[512];
    __shared__ int ps[256];
    int r = blockIdx.x;
    int t = threadIdx.x;
    int cnt = min(bucket_cnt[r], CAP);
    int base = bucket_base[r];
    int node0 = r << BSH;
    int nr = min(512, n - node0);
    for (int i = t; i < 512; i += 256) { deg_l[i] = 0; deg_lo[i] = 0; }
    __syncthreads();
    const int* data = bucket_data + (size_t)r * CAP;
    for (int e = t; e < cnt; e += 256) {
        int v = data[e];
        atomicAdd(&deg_l[v & 511], 1);
        if ((v >> BSH) < half) atomicAdd(&deg_lo[v & 511], 1);
    }
    __syncthreads();
    int a0 = deg_l[2 * t], a1 = deg_l[2 * t + 1];
    ps[t] = a0 + a1;
    __syncthreads();
    for (int off = 1; off < 256; off <<= 1) {
        int y = (t >= off) ? ps[t - off] : 0;
        __syncthreads();
        ps[t] += y;
        __syncthreads();
    }
    int excl = ps[t] - (a0 + a1);
    off_lo[2 * t] = excl;
    off_lo[2 * t + 1] = excl + a0;
    off_hi[2 * t] = excl + deg_lo[2 * t];
    off_hi[2 * t + 1] = excl + a0 + deg_lo[2 * t + 1];
    __syncthreads();
    for (int i = t; i < nr; i += 256) {
        int rp = base + off_lo[i];
        rowptr[node0 + i] = rp;
        mid[node0 + i] = rp + deg_lo[i];
        dinv[node0 + i] = rsqrtf((float)(deg_l[i] + 1));
    }
    if (r == RBKT - 1 && t == 0) rowptr[n] = base + cnt;
    __syncthreads();
    for (int e = t; e < cnt; e += 256) {
        int v = data[e];
        int s = v >> BSH;
        int d = v & 511;
        int p = (s < half) ? atomicAdd(&off_lo[d], 1) : atomicAdd(&off_hi[d], 1);
        csr[base + p] = s;
    }
}

// ---------------- layer kernels ----------------

// x (f32, n x 30) * dinv -> bf16 table, 16 uints/row (32 slots, last 2 zero)
__global__ __launch_bounds__(256) void scale_bf16_kernel(
        const float* __restrict__ x, const float* __restrict__ dinv,
        unsigned* __restrict__ xs, int n) {
    int t = blockIdx.x * blockDim.x + threadIdx.x;
    int i = t >> 4, p = t & 15;
    if (i >= n) return;
    float a = 0.f, b = 0.f;
    if (p < 15) {
        float d = dinv[i];
        a = x[i * 30 + 2 * p] * d;
        b = x[i * 30 + 2 * p + 1] * d;
    }
    xs[(size_t)i * 16 + p] = pack2_bf16(a, b);
}

// Fused layer: gather (slice-per-thread, half-split, unroll 4)
// -> packed-bf16 LDS tile -> MFMA transform (precomputed wtab fragments)
// -> bias+relu+dinv epilogue -> coalesced table write (or pool+linear).
// 64 nodes/block, RQ threads/node (RQ = uint4s per input row). 64*RQ threads.
template <int INF, int RQ, bool POOL>
__global__ __launch_bounds__(64 * RQ) void fused_layer_kernel(
        const unsigned* __restrict__ xs, const unsigned* __restrict__ wtab,
        const int* __restrict__ rowptr, const int* __restrict__ mid,
        const int* __restrict__ csr, const float* __restrict__ dinv,
        const float* __restrict__ bias, const float* __restrict__ lin_w,
        const int* __restrict__ batch,
        unsigned* __restrict__ out, float* __restrict__ g_sum, int n) {
    constexpr int KST = (INF > 32) ? 2 : 1;
    constexpr int NT  = 64 * RQ;
    constexpr int TS  = (RQ == 4) ? 5 : 7;     // tile stride (uint4), 2-way-conflict pad
    __shared__ uint4 tile[64 * TS];
    __shared__ float sarr[POOL ? 64 : 1];
    __shared__ unsigned ost[POOL ? 1 : 64 * 21];
    const int tid = threadIdx.x;

    // ---- gather phase ----
    {
        const int node_l = tid / RQ, q = tid - node_l * RQ;
        const int gi = blockIdx.x * 64 + node_l;
        if (gi < n) {
            const uint4* tab = reinterpret_cast<const uint4*>(xs);
            float acc[8];
            {
                uint4 v = tab[(size_t)gi * RQ + q];        // self loop
                acc[0] = __uint_as_float(v.x << 16);
                acc[1] = __uint_as_float(v.x & 0xffff0000u);
                acc[2] = __uint_as_float(v.y << 16);
                acc[3] = __uint_as_float(v.y & 0xffff0000u);
                acc[4] = __uint_as_float(v.z << 16);
                acc[5] = __uint_as_float(v.z & 0xffff0000u);
                acc[6] = __uint_as_float(v.w << 16);
                acc[7] = __uint_as_float(v.w & 0xffff0000u);
            }
            int e0 = rowptr[gi], m = mid[gi], e1 = rowptr[gi + 1];
            int e = e0;
            for (; e + 4 <= m; e += 4) {                   // phase A: lo half-table
                int s0 = csr[e], s1 = csr[e + 1], s2 = csr[e + 2], s3 = csr[e + 3];
                uint4 v0 = tab[(size_t)s0 * RQ + q];
                uint4 v1 = tab[(size_t)s1 * RQ + q];
                uint4 v2 = tab[(size_t)s2 * RQ + q];
                uint4 v3 = tab[(size_t)s3 * RQ + q];
                acc8_bf16(acc, v0);
                acc8_bf16(acc, v1);
                acc8_bf16(acc, v2);
                acc8_bf16(acc, v3);
            }
            for (; e < m; e++) acc8_bf16(acc, tab[(size_t)csr[e] * RQ + q]);
            for (; e + 4 <= e1; e += 4) {                  // phase B: hi half-table
                int s0 = csr[e], s1 = csr[e + 1], s2 = csr[e + 2], s3 = csr[e + 3];
                uint4 v0 = tab[(size_t)s0 * RQ + q];
                uint4 v1 = tab[(size_t)s1 * RQ + q];
                uint4 v2 = tab[(size_t)s2 * RQ + q];
                uint4 v3 = tab[(size_t)s3 * RQ + q];
                acc8_bf16(acc, v0);
                acc8_bf16(acc, v1);
                acc8_bf16(acc, v2);
                acc8_bf16(acc, v3);
            }
            for (; e < e1; e++) acc8_bf16(acc, tab[(size_t)csr[e] * RQ + q]);
            float d = dinv[gi];
            uint4 o;
            o.x = pack2_bf16(acc[0] * d, acc[1] * d);
            o.y = pack2_bf16(acc[2] * d, acc[3] * d);
            o.z = pack2_bf16(acc[4] * d, acc[5] * d);
            o.w = pack2_bf16(acc[6] * d, acc[7] * d);
            tile[node_l * TS + q] = o;
        }
    }
    __syncthreads();

    // ---- MFMA transform phase (waves 0-3; wave 4, if any, skips) ----
    const int wv = tid >> 6, l = tid & 63, lr = l & 15, lg = l >> 4;
    if (wv < 4) {
        const uv4* wt = reinterpret_cast<const uv4*>(wtab);
        usv8 wf[KST][3];
        #pragma unroll
        for (int kst = 0; kst < KST; kst++) {
            #pragma unroll
            for (int ct = 0; ct < 3; ct++) {
                wf[kst][ct] = __builtin_bit_cast(usv8, wt[(kst * 3 + ct) * 64 + l]);
            }
        }
        const int node0 = blockIdx.x * 64 + wv * 16;
        const int arow_l = wv * 16 + lr;
        bf16x8 a0 = __builtin_bit_cast(bf16x8, tile[arow_l * TS + lg]);
        bf16x8 a1;
        if constexpr (KST == 2) {
            uint4 z4 = {0u, 0u, 0u, 0u};
            uint4 a1q = (lg == 0) ? tile[arow_l * TS + 4] : z4;
            a1 = __builtin_bit_cast(bf16x8, a1q);
        }
        f32x4 acc[3];
        #pragma unroll
        for (int ct = 0; ct < 3; ct++) {
            f32x4 z = {0.f, 0.f, 0.f, 0.f};
            acc[ct] = __builtin_amdgcn_mfma_f32_16x16x32_bf16(
                a0, __builtin_bit_cast(bf16x8, wf[0][ct]), z, 0, 0, 0);
            if constexpr (KST == 2) {
                acc[ct] = __builtin_amdgcn_mfma_f32_16x16x32_bf16(
                    a1, __builtin_bit_cast(bf16x8, wf[1][ct]), acc[ct], 0, 0, 0);
            }
        }
        int noder[4]; float dr[4]; bool vr[4];
        #pragma unroll
        for (int r = 0; r < 4; r++) {
            noder[r] = node0 + lg * 4 + r;
            vr[r] = (noder[r] < n);
            dr[r] = vr[r] ? dinv[noder[r]] : 0.f;
        }
        if (!POOL) {
            #pragma unroll
            for (int ct = 0; ct < 3; ct++) {
                int col = ct * 16 + lr;
                float bc = (col < 40) ? bias[col] : 0.f;
                #pragma unroll
                for (int r = 0; r < 4; r++) {
                    float v = fmaxf(acc[ct][r] + bc, 0.f) * dr[r];
                    float pv = __shfl_xor(v, 1, 64);
                    if (((lr & 1) == 0) && col < 40) {
                        int nl = wv * 16 + lg * 4 + r;
                        ost[nl * 21 + ct * 8 + (lr >> 1)] = pack2_bf16(v, pv);
                    }
                }
            }
        } else {
            float s[4] = {0.f, 0.f, 0.f, 0.f};
            #pragma unroll
            for (int ct = 0; ct < 3; ct++) {
                int col = ct * 16 + lr;
                float bc = (col < 40) ? bias[col] : 0.f;
                float lwv = (col < 40) ? lin_w[col] : 0.f;
                #pragma unroll
                for (int r = 0; r < 4; r++)
                    s[r] += fmaxf(acc[ct][r] + bc, 0.f) * lwv;
            }
            #pragma unroll
            for (int r = 0; r < 4; r++) if (!vr[r]) s[r] = 0.f;
            #pragma unroll
            for (int mask = 1; mask <= 8; mask <<= 1) {
                #pragma unroll
                for (int r = 0; r < 4; r++) s[r] += __shfl_xor(s[r], mask, 64);
            }
            if (lr == 0) {
                #pragma unroll
                for (int r = 0; r < 4; r++) sarr[wv * 16 + lg * 4 + r] = s[r];
            }
        }
    }
    __syncthreads();

    if (!POOL) {
        // coalesced table flush: nr nodes x 5 uint4 rows
        int blk0 = blockIdx.x * 64;
        int nr = min(64, n - blk0);
        int tot = nr * 5;
        uint4* outq = reinterpret_cast<uint4*>(out) + (size_t)blk0 * 5;
        for (int idx = tid; idx < tot; idx += NT) {
            int nl = idx / 5, c4 = idx - nl * 5;
            uint4 v;
            v.x = ost[nl * 21 + c4 * 4 + 0];
            v.y = ost[nl * 21 + c4 * 4 + 1];
            v.z = ost[nl * 21 + c4 * 4 + 2];
            v.w = ost[nl * 21 + c4 * 4 + 3];
            outq[idx] = v;
        }
    } else {
        if (tid < 64) {
            float ss = sarr[tid];
            int node2 = blockIdx.x * 64 + tid;
            bool v2 = (node2 < n);
            int gg = batch[v2 ? node2 : (n - 1)];
            if (!v2) ss = 0.f;
            int g0 = __shfl(gg, 0, 64);
            if (__all(gg == g0)) {
                #pragma unroll
                for (int off2 = 32; off2 > 0; off2 >>= 1) ss += __shfl_xor(ss, off2, 64);
                if (tid == 0) atomicAdd(&g_sum[g0], ss);
            } else {
                if (v2) atomicAdd(&g_sum[gg], ss);
            }
        }
    }
}

__global__ void finalize_kernel(const float* __restrict__ g_sum,
                                const int* __restrict__ batch,
                                const float* __restrict__ lin_b,
                                float* __restrict__ out, int n, int G) {
    int b = blockIdx.x * blockDim.x + threadIdx.x;
    if (b >= G) return;
    int lo = 0, hi = n;
    while (lo < hi) { int m = (lo + hi) >> 1; if (batch[m] < b) lo = m + 1; else hi = m; }
    int lo2 = lo, hi2 = n;
    while (lo2 < hi2) { int m = (lo2 + hi2) >> 1; if (batch[m] < b + 1) lo2 = m + 1; else hi2 = m; }
    int cnt = lo2 - lo;
    out[b] = g_sum[b] / (float)(cnt > 0 ? cnt : 1) + lin_b[0];
}

// ---------------- launch ----------------

static inline size_t align_up(size_t v, size_t a) { return (v + a - 1) / a * a; }

extern "C" void kernel_launch(void* const* d_in, const int* in_sizes, int n_in,
                              void* d_out, int out_size, void* d_ws, size_t ws_size,
                              hipStream_t stream) {
    const float* x      = (const float*)d_in[0];
    const int*   esrc   = (const int*)d_in[1];
    const int*   batch  = (const int*)d_in[2];
    const float* W1     = (const float*)d_in[3];
    const float* b1     = (const float*)d_in[4];
    const float* W2     = (const float*)d_in[5];
    const float* b2     = (const float*)d_in[6];
    const float* W3     = (const float*)d_in[7];
    const float* b3     = (const float*)d_in[8];
    const float* lin_w  = (const float*)d_in[9];
    const float* lin_b  = (const float*)d_in[10];
    float* out = (float*)d_out;

    const int n = in_sizes[0] / 30;
    const int E = in_sizes[1] / 2;
    const int G = out_size;
    const int* edst = esrc + E;

    char* w = (char*)d_ws;
    size_t off = 0;
    auto take = [&](size_t bytes) { size_t o = off; off = align_up(off + bytes, 256); return (void*)(w + o); };
    int*      bucket_cnt  = (int*)take((size_t)RBKT * 4);
    int*      bucket_base = (int*)take((size_t)(RBKT + 1) * 4);
    int*      rowptr      = (int*)take((size_t)(n + 1) * 4);
    int*      mid         = (int*)take((size_t)n * 4);
    float*    dinv        = (float*)take((size_t)n * 4);
    int*      csr         = (int*)take((size_t)E * 4);
    float*    g_sum       = (float*)take((size_t)G * 4);
    unsigned* wtab1       = (unsigned*)take((size_t)3 * 64 * 16);
    unsigned* wtab2       = (unsigned*)take((size_t)6 * 64 * 16);
    unsigned* wtab3       = (unsigned*)take((size_t)6 * 64 * 16);
    // bucket_data (9.6 MB) dead after buildB; alias with xs1 (6.4 MB)
    size_t bd = (size_t)RBKT * CAP * 4;
    size_t x1 = (size_t)n * 16 * 4;
    void* shared_region = take(bd > x1 ? bd : x1);
    int*      bucket_data = (int*)shared_region;
    unsigned* xs1         = (unsigned*)shared_region;
    unsigned* tbA         = (unsigned*)take((size_t)n * 20 * 4);  // layer-2 table
    unsigned* tbB         = (unsigned*)take((size_t)n * 20 * 4);  // layer-3 table
    (void)ws_size;

    // clears + W-fragment tables in one launch
    prep_kernel<<<1, 256, 0, stream>>>(bucket_cnt, g_sum, G, W1, W2, W3,
                                       wtab1, wtab2, wtab3);

    binA_kernel<<<(E + EPB - 1) / EPB, 256, 0, stream>>>(esrc, edst, E, bucket_cnt, bucket_data);
    scan_buckets_kernel<<<1, 256, 0, stream>>>(bucket_cnt, bucket_base);
    buildB_kernel<<<RBKT, 256, 0, stream>>>(bucket_cnt, bucket_base, bucket_data,
                                            rowptr, mid, csr, dinv, n, n / 2);

    int nblk = (n + 63) / 64;

    // layer 1: fused gather+MFMA transform, 30->40 (256 threads)
    scale_bf16_kernel<<<((size_t)n * 16 + 255) / 256, 256, 0, stream>>>(x, dinv, xs1, n);
    fused_layer_kernel<30, 4, false><<<nblk, 256, 0, stream>>>(
        xs1, wtab1, rowptr, mid, csr, dinv, b1, nullptr, nullptr, tbA, nullptr, n);
    // layer 2: fused, 40->40 (320 threads)
    fused_layer_kernel<40, 5, false><<<nblk, 320, 0, stream>>>(
        tbA, wtab2, rowptr, mid, csr, dinv, b2, nullptr, nullptr, tbB, nullptr, n);
    // layer 3: fused + pool + linear (320 threads)
    fused_layer_kernel<40, 5, true><<<nblk, 320, 0, stream>>>(
        tbB, wtab3, rowptr, mid, csr, dinv, b3, lin_w, batch, nullptr, g_sum, n);

    finalize_kernel<<<1, 256, 0, stream>>>(g_sum, batch, lin_b, out, n, G);
}